// Round 1
// baseline (4827.459 us; speedup 1.0000x reference)
//
#include <hip/hip_runtime.h>
#include <hip/hip_bf16.h>

#define D_ 64
#define NH_ 4
#define DH_ 16
#define FF_ 2048
#define V_ 1000000
#define STEPS_ 10
#define EPS_ 1e-5f
#define CHUNK_ 1024

// ---------------------------------------------------------------------------
// Monotone packing of (logit value, index) into u64 so a single atomicMax
// implements argmax with jnp.argmax tie-breaking (first/lowest index wins).
// ---------------------------------------------------------------------------
__device__ __forceinline__ unsigned long long pack_best(float v, int idx) {
    unsigned u = __float_as_uint(v);
    u = (u & 0x80000000u) ? ~u : (u | 0x80000000u);   // monotone float->uint
    return ((unsigned long long)u << 32) | (unsigned long long)(~(unsigned)idx);
}

__device__ __forceinline__ int unpack_idx(unsigned long long p) {
    return (int)(~(unsigned)(p & 0xFFFFFFFFull));
}

__global__ void init_kernel(unsigned long long* bp) {
    if (threadIdx.x < 16) bp[threadIdx.x] = 0ull;
}

// ---------------------------------------------------------------------------
// Single-block encoder: builds the S=t+1 sequence, runs both transformer
// layers entirely in LDS, writes x_last (64 floats) for the logits kernel.
// Also decodes the previous step's argmax (bp[t-1]) -> gen_idx[t-1] and the
// float gen output.
// ---------------------------------------------------------------------------
__global__ __launch_bounds__(1024) void encoder_kernel(
    const float* __restrict__ ht, const float* __restrict__ item_emb,
    const float* __restrict__ pos_emb,
    const float* __restrict__ ipw, const float* __restrict__ ipb,
    const float* __restrict__ ow,  const float* __restrict__ ob,
    const float* __restrict__ l1w, const float* __restrict__ l1b,
    const float* __restrict__ l2w, const float* __restrict__ l2b,
    const float* __restrict__ f1w, const float* __restrict__ f1b,
    const float* __restrict__ f2w, const float* __restrict__ f2b,
    unsigned long long* __restrict__ bp, int* __restrict__ gen_idx,
    float* __restrict__ x_last, float* __restrict__ gen_out, int t)
{
    const int S = t + 1;
    const int tid = threadIdx.x;

    __shared__ float x[10 * 64];        // layer input / post-LN activations
    __shared__ float qkv[10 * 192];
    __shared__ float attn[4 * 10 * 10];
    __shared__ float o_[10 * 64];
    __shared__ float y[10 * 64];        // pre-LN (residual sum)
    __shared__ float hbuf[CHUNK_ * 10]; // FFN hidden chunk, layout [j_local][s]
    __shared__ float row_m[10], row_r[10];

    // Decode previous step's argmax (device-visible via stream ordering).
    if (t > 0 && tid == 0) {
        int idx = unpack_idx(bp[t - 1]);
        gen_idx[t - 1] = idx;
        gen_out[t - 1] = (float)idx;
    }
    __syncthreads();

    // Build x = stack + pos_emb[:S]
    for (int i = tid; i < S * 64; i += 1024) {
        int s = i >> 6, d = i & 63;
        float base = (s == 0) ? ht[d] : item_emb[(size_t)gen_idx[s - 1] * 64 + d];
        x[i] = base + pos_emb[s * 64 + d];
    }
    __syncthreads();

    for (int l = 0; l < 2; l++) {
        // ---- QKV projection: qkv[s][j] = x[s] . ipw[l][j] + ipb[l][j]
        const float* W = ipw + l * 192 * 64;
        for (int i = tid; i < S * 192; i += 1024) {
            int s = i / 192, j = i % 192;
            float acc = ipb[l * 192 + j];
            const float* wr = W + j * 64;
            const float* xr = x + s * 64;
            #pragma unroll 8
            for (int k = 0; k < 64; k++) acc += xr[k] * wr[k];
            qkv[s * 192 + j] = acc;
        }
        __syncthreads();

        // ---- scores[h][si][ti] = q.k / sqrt(16)
        for (int i = tid; i < 4 * S * S; i += 1024) {
            int h = i / (S * S); int r = i % (S * S);
            int si = r / S, ti = r % S;
            const float* qr = qkv + si * 192 + h * 16;
            const float* kr = qkv + ti * 192 + 64 + h * 16;
            float acc = 0.f;
            #pragma unroll
            for (int k = 0; k < 16; k++) acc += qr[k] * kr[k];
            attn[(h * S + si) * S + ti] = acc * 0.25f;
        }
        __syncthreads();

        // ---- softmax over ti (one thread per (h,si) row)
        for (int i = tid; i < 4 * S; i += 1024) {
            float* row = attn + i * S;
            float mx = row[0];
            for (int j = 1; j < S; j++) mx = fmaxf(mx, row[j]);
            float sm = 0.f;
            for (int j = 0; j < S; j++) { float e = expf(row[j] - mx); row[j] = e; sm += e; }
            float inv = 1.0f / sm;
            for (int j = 0; j < S; j++) row[j] *= inv;
        }
        __syncthreads();

        // ---- o[s][h*16+dh] = sum_ti attn * v
        for (int i = tid; i < S * 64; i += 1024) {
            int si = i >> 6, d = i & 63; int h = d >> 4; int dh = d & 15;
            const float* ar = attn + (h * S + si) * S;
            float acc = 0.f;
            for (int ti = 0; ti < S; ti++)
                acc += ar[ti] * qkv[ti * 192 + 128 + h * 16 + dh];
            o_[i] = acc;
        }
        __syncthreads();

        // ---- out proj + residual: y = o @ ow.T + ob + x
        const float* OW = ow + l * 64 * 64;
        for (int i = tid; i < S * 64; i += 1024) {
            int s = i >> 6, d = i & 63;
            float acc = ob[l * 64 + d] + x[i];
            const float* wr = OW + d * 64;
            const float* orow = o_ + s * 64;
            #pragma unroll 8
            for (int k = 0; k < 64; k++) acc += orow[k] * wr[k];
            y[i] = acc;
        }
        __syncthreads();

        // ---- LN1 stats
        if (tid < S) {
            const float* yr = y + tid * 64;
            float m = 0.f;
            for (int k = 0; k < 64; k++) m += yr[k];
            m *= (1.0f / 64.0f);
            float v = 0.f;
            for (int k = 0; k < 64; k++) { float df = yr[k] - m; v += df * df; }
            v *= (1.0f / 64.0f);
            row_m[tid] = m;
            row_r[tid] = 1.0f / sqrtf(v + EPS_);
        }
        __syncthreads();
        for (int i = tid; i < S * 64; i += 1024) {
            int s = i >> 6, d = i & 63;
            x[i] = (y[i] - row_m[s]) * row_r[s] * l1w[l * 64 + d] + l1b[l * 64 + d];
        }
        __syncthreads();

        // ---- FFN, chunked over hidden dim (2 x 1024) to fit LDS.
        // Threads tid < S*64 own output element (s,d) and accumulate in regs.
        float acc2 = 0.f;
        const int own_s = tid >> 6, own_d = tid & 63;
        const bool owner = tid < S * 64;
        const float* F1 = f1w + l * 2048 * 64;
        const float* F2 = f2w + l * 64 * 2048;
        for (int c = 0; c < 2; c++) {
            // FFN1: hidden unit j = c*1024 + tid, all S rows
            {
                int j = c * 1024 + tid;
                const float4* wr4 = (const float4*)(F1 + (size_t)j * 64);
                float b1 = f1b[l * 2048 + j];
                for (int s = 0; s < S; s++) {
                    const float4* xr4 = (const float4*)(x + s * 64);
                    float a = b1;
                    #pragma unroll
                    for (int k = 0; k < 16; k++) {
                        float4 w = wr4[k]; float4 xv = xr4[k];
                        a += w.x * xv.x + w.y * xv.y + w.z * xv.z + w.w * xv.w;
                    }
                    hbuf[tid * 10 + s] = fmaxf(a, 0.f);
                }
            }
            __syncthreads();
            // FFN2 partial: acc2 += f2w[d][c*1024 .. +1024] . h[..][s]
            if (owner) {
                const float4* w4 = (const float4*)(F2 + (size_t)own_d * 2048 + c * 1024);
                #pragma unroll 4
                for (int k4 = 0; k4 < 256; k4++) {
                    float4 w = w4[k4];
                    int k = k4 * 4;
                    acc2 += w.x * hbuf[(k + 0) * 10 + own_s]
                          + w.y * hbuf[(k + 1) * 10 + own_s]
                          + w.z * hbuf[(k + 2) * 10 + own_s]
                          + w.w * hbuf[(k + 3) * 10 + own_s];
                }
            }
            __syncthreads();
        }
        if (owner) y[tid] = acc2 + f2b[l * 64 + own_d] + x[tid];
        __syncthreads();

        // ---- LN2
        if (tid < S) {
            const float* yr = y + tid * 64;
            float m = 0.f;
            for (int k = 0; k < 64; k++) m += yr[k];
            m *= (1.0f / 64.0f);
            float v = 0.f;
            for (int k = 0; k < 64; k++) { float df = yr[k] - m; v += df * df; }
            v *= (1.0f / 64.0f);
            row_m[tid] = m;
            row_r[tid] = 1.0f / sqrtf(v + EPS_);
        }
        __syncthreads();
        for (int i = tid; i < S * 64; i += 1024) {
            int s = i >> 6, d = i & 63;
            x[i] = (y[i] - row_m[s]) * row_r[s] * l2w[l * 64 + d] + l2b[l * 64 + d];
        }
        __syncthreads();
    }

    if (tid < 64) x_last[tid] = x[(S - 1) * 64 + tid];
}

// ---------------------------------------------------------------------------
// logits[row] = x_last . item_emb[row], row in [0, V). 16 lanes per row,
// float4 loads (wave reads 1KB contiguous covering 4 rows). Block-local best
// -> one atomicMax per block on the packed (value, ~idx) u64.
// ---------------------------------------------------------------------------
__global__ __launch_bounds__(256) void logits_kernel(
    const float* __restrict__ item_emb, const float* __restrict__ x_last,
    float* __restrict__ out, unsigned long long* __restrict__ best)
{
    const int tid = threadIdx.x;
    const int l16 = tid & 15;
    float4 q = ((const float4*)x_last)[l16];
    const int group0 = (blockIdx.x * 256 + tid) >> 4;
    const int ngroups = (gridDim.x * 256) >> 4;
    unsigned long long lb = 0ull;

    for (int row = group0; row < V_; row += ngroups) {
        float4 e = ((const float4*)(item_emb + (size_t)row * 64))[l16];
        float p = q.x * e.x + q.y * e.y + q.z * e.z + q.w * e.w;
        p += __shfl_xor(p, 1);
        p += __shfl_xor(p, 2);
        p += __shfl_xor(p, 4);
        p += __shfl_xor(p, 8);
        if (l16 == 0) {
            out[row] = p;
            unsigned long long pk = pack_best(p, row);
            if (pk > lb) lb = pk;
        }
    }

    __shared__ unsigned long long sb[16];
    if (l16 == 0) sb[tid >> 4] = lb;
    __syncthreads();
    if (tid == 0) {
        unsigned long long b = sb[0];
        #pragma unroll
        for (int i = 1; i < 16; i++) b = (sb[i] > b) ? sb[i] : b;
        atomicMax(best, b);
    }
}

__global__ void finalize_kernel(const unsigned long long* __restrict__ bp,
                                int* __restrict__ gen_idx,
                                float* __restrict__ gen_out) {
    if (threadIdx.x == 0) {
        int idx = unpack_idx(bp[STEPS_ - 1]);
        gen_idx[STEPS_ - 1] = idx;
        gen_out[STEPS_ - 1] = (float)idx;
    }
}

extern "C" void kernel_launch(void* const* d_in, const int* in_sizes, int n_in,
                              void* d_out, int out_size, void* d_ws, size_t ws_size,
                              hipStream_t stream) {
    const float* ht       = (const float*)d_in[0];
    const float* item_emb = (const float*)d_in[1];
    const float* pos_emb  = (const float*)d_in[2];
    const float* ipw      = (const float*)d_in[3];
    const float* ipb      = (const float*)d_in[4];
    const float* ow       = (const float*)d_in[5];
    const float* ob       = (const float*)d_in[6];
    const float* l1w      = (const float*)d_in[7];
    const float* l1b      = (const float*)d_in[8];
    const float* l2w      = (const float*)d_in[9];
    const float* l2b      = (const float*)d_in[10];
    const float* f1w      = (const float*)d_in[11];
    const float* f1b      = (const float*)d_in[12];
    const float* f2w      = (const float*)d_in[13];
    const float* f2b      = (const float*)d_in[14];

    float* out = (float*)d_out;
    char* ws = (char*)d_ws;
    unsigned long long* bp = (unsigned long long*)ws;      // 16 x u64
    int* gen_idx = (int*)(ws + 128);                       // 16 x i32
    float* x_last = (float*)(ws + 256);                    // 64 x f32
    float* gen_out = out + (size_t)STEPS_ * V_;

    init_kernel<<<1, 64, 0, stream>>>(bp);
    for (int t = 0; t < STEPS_; t++) {
        encoder_kernel<<<1, 1024, 0, stream>>>(
            ht, item_emb, pos_emb, ipw, ipb, ow, ob,
            l1w, l1b, l2w, l2b, f1w, f1b, f2w, f2b,
            bp, gen_idx, x_last, gen_out, t);
        logits_kernel<<<2048, 256, 0, stream>>>(
            item_emb, x_last, out + (size_t)t * V_, bp + t);
    }
    finalize_kernel<<<1, 64, 0, stream>>>(bp, gen_idx, gen_out);
}

// Round 2
// 1397.966 us; speedup vs baseline: 3.4532x; 3.4532x over previous
//
#include <hip/hip_runtime.h>
#include <hip/hip_bf16.h>

#define D_ 64
#define NH_ 4
#define DH_ 16
#define FF_ 2048
#define V_ 1000000
#define STEPS_ 10
#define EPS_ 1e-5f

// ---------------------------------------------------------------------------
// Monotone packing of (logit value, index) into u64 so a single atomicMax
// implements argmax with jnp.argmax tie-breaking (lowest index wins).
// ---------------------------------------------------------------------------
__device__ __forceinline__ unsigned long long pack_best(float v, int idx) {
    unsigned u = __float_as_uint(v);
    u = (u & 0x80000000u) ? ~u : (u | 0x80000000u);
    return ((unsigned long long)u << 32) | (unsigned long long)(~(unsigned)idx);
}
__device__ __forceinline__ int unpack_idx(unsigned long long p) {
    return (int)(~(unsigned)(p & 0xFFFFFFFFull));
}

__global__ void init_kernel(unsigned long long* bp) {
    if (threadIdx.x < 16) bp[threadIdx.x] = 0ull;
}

// ---------------------------------------------------------------------------
// Attention kernel (1 block, 1024 threads): for l==0 builds the sequence
// (decoding the previous step's argmax), for l==1 applies layer-0 LN2 to
// y_in first. Then QKV, softmax-attention, out-proj + residual, LN1.
// Writes the post-LN1 activation xp (S x 64) to ws for the FFN kernels.
// Weight footprint: ipw 48KB + ow 16KB -> small cold-fetch, 16 waves of MLP.
// ---------------------------------------------------------------------------
__global__ __launch_bounds__(1024) void attn_kernel(
    const float* __restrict__ ht, const float* __restrict__ item_emb,
    const float* __restrict__ pos_emb,
    const float* __restrict__ ipw, const float* __restrict__ ipb,
    const float* __restrict__ ow,  const float* __restrict__ ob,
    const float* __restrict__ l1w, const float* __restrict__ l1b,
    const float* __restrict__ pl2w, const float* __restrict__ pl2b, // prev-layer LN2 (l==1)
    unsigned long long* __restrict__ bp, int* __restrict__ gen_idx,
    const float* __restrict__ y_in, float* __restrict__ xp_out,
    float* __restrict__ gen_out, int t, int l)
{
    const int S = t + 1;
    const int tid = threadIdx.x;

    __shared__ float x[10 * 64];
    __shared__ float qkv[10 * 192];
    __shared__ float attn[4 * 10 * 10];
    __shared__ float o_[10 * 64];
    __shared__ float y2[10 * 64];
    __shared__ float row_m[10], row_r[10];

    if (l == 0) {
        if (t > 0 && tid == 0) {
            int idx = unpack_idx(bp[t - 1]);
            gen_idx[t - 1] = idx;
            gen_out[t - 1] = (float)idx;
        }
        __syncthreads();
        for (int i = tid; i < S * 64; i += 1024) {
            int s = i >> 6, d = i & 63;
            float base = (s == 0) ? ht[d] : item_emb[(size_t)gen_idx[s - 1] * 64 + d];
            x[i] = base + pos_emb[i];
        }
    } else {
        // LN2 of previous layer's y
        if (tid < S) {
            const float* yr = y_in + tid * 64;
            float m = 0.f;
            for (int k = 0; k < 64; k++) m += yr[k];
            m *= (1.0f / 64.0f);
            float v = 0.f;
            for (int k = 0; k < 64; k++) { float df = yr[k] - m; v += df * df; }
            v *= (1.0f / 64.0f);
            row_m[tid] = m;
            row_r[tid] = 1.0f / sqrtf(v + EPS_);
        }
        __syncthreads();
        for (int i = tid; i < S * 64; i += 1024) {
            int s = i >> 6, d = i & 63;
            x[i] = (y_in[i] - row_m[s]) * row_r[s] * pl2w[d] + pl2b[d];
        }
    }
    __syncthreads();

    // QKV projection
    const float* W = ipw + l * 192 * 64;
    for (int i = tid; i < S * 192; i += 1024) {
        int s = i / 192, j = i % 192;
        float acc = ipb[l * 192 + j];
        const float4* wr = (const float4*)(W + j * 64);
        const float4* xr = (const float4*)(x + s * 64);
        #pragma unroll
        for (int k = 0; k < 16; k++) {
            float4 w4 = wr[k]; float4 xv = xr[k];
            acc += w4.x * xv.x + w4.y * xv.y + w4.z * xv.z + w4.w * xv.w;
        }
        qkv[s * 192 + j] = acc;
    }
    __syncthreads();

    // scores
    for (int i = tid; i < 4 * S * S; i += 1024) {
        int h = i / (S * S); int r = i % (S * S);
        int si = r / S, ti = r % S;
        const float* qr = qkv + si * 192 + h * 16;
        const float* kr = qkv + ti * 192 + 64 + h * 16;
        float acc = 0.f;
        #pragma unroll
        for (int k = 0; k < 16; k++) acc += qr[k] * kr[k];
        attn[(h * S + si) * S + ti] = acc * 0.25f;
    }
    __syncthreads();

    // softmax rows
    for (int i = tid; i < 4 * S; i += 1024) {
        float* row = attn + i * S;
        float mx = row[0];
        for (int j = 1; j < S; j++) mx = fmaxf(mx, row[j]);
        float sm = 0.f;
        for (int j = 0; j < S; j++) { float e = expf(row[j] - mx); row[j] = e; sm += e; }
        float inv = 1.0f / sm;
        for (int j = 0; j < S; j++) row[j] *= inv;
    }
    __syncthreads();

    // o = attn @ v
    for (int i = tid; i < S * 64; i += 1024) {
        int si = i >> 6, d = i & 63; int h = d >> 4; int dh = d & 15;
        const float* ar = attn + (h * S + si) * S;
        float acc = 0.f;
        for (int ti = 0; ti < S; ti++)
            acc += ar[ti] * qkv[ti * 192 + 128 + h * 16 + dh];
        o_[i] = acc;
    }
    __syncthreads();

    // out-proj + residual
    const float* OW = ow + l * 64 * 64;
    for (int i = tid; i < S * 64; i += 1024) {
        int s = i >> 6, d = i & 63;
        float acc = ob[l * 64 + d] + x[i];
        const float4* wr = (const float4*)(OW + d * 64);
        const float4* orow = (const float4*)(o_ + s * 64);
        #pragma unroll
        for (int k = 0; k < 16; k++) {
            float4 w4 = wr[k]; float4 ov = orow[k];
            acc += w4.x * ov.x + w4.y * ov.y + w4.z * ov.z + w4.w * ov.w;
        }
        y2[i] = acc;
    }
    __syncthreads();

    // LN1 -> xp_out (global, consumed by FFN kernels)
    if (tid < S) {
        const float* yr = y2 + tid * 64;
        float m = 0.f;
        for (int k = 0; k < 64; k++) m += yr[k];
        m *= (1.0f / 64.0f);
        float v = 0.f;
        for (int k = 0; k < 64; k++) { float df = yr[k] - m; v += df * df; }
        v *= (1.0f / 64.0f);
        row_m[tid] = m;
        row_r[tid] = 1.0f / sqrtf(v + EPS_);
    }
    __syncthreads();
    for (int i = tid; i < S * 64; i += 1024) {
        int s = i >> 6, d = i & 63;
        xp_out[i] = (y2[i] - row_m[s]) * row_r[s] * l1w[l * 64 + d] + l1b[l * 64 + d];
    }
}

// ---------------------------------------------------------------------------
// FFN1: h[s][j] = relu(f1w[j] . xp[s] + b1[j]). 128 blocks x 256 threads;
// block handles 16 hidden units, 16 lanes k-split each (4 KB of weights per
// block, one coalesced fetch). hbuf layout [s][j].
// ---------------------------------------------------------------------------
__global__ __launch_bounds__(256) void ffn1_kernel(
    const float* __restrict__ f1w, const float* __restrict__ f1b,
    const float* __restrict__ xp, float* __restrict__ hbuf, int S, int l)
{
    const int tid = threadIdx.x;
    __shared__ float xs[10 * 64];
    for (int i = tid; i < S * 64; i += 256) xs[i] = xp[i];
    __syncthreads();

    const int j = blockIdx.x * 16 + (tid >> 4);
    const int kp = tid & 15;
    float4 w = ((const float4*)(f1w + (size_t)(l * 2048 + j) * 64))[kp];
    float b = f1b[l * 2048 + j];

    for (int s = 0; s < S; s++) {
        float4 xv = ((const float4*)(xs + s * 64))[kp];
        float p = w.x * xv.x + w.y * xv.y + w.z * xv.z + w.w * xv.w;
        p += __shfl_xor(p, 1);
        p += __shfl_xor(p, 2);
        p += __shfl_xor(p, 4);
        p += __shfl_xor(p, 8);
        if (kp == 0) hbuf[s * 2048 + j] = fmaxf(p + b, 0.f);
    }
}

// ---------------------------------------------------------------------------
// FFN2: y[s][d] = f2w[d] . h[s] + b2[d] + xp[s][d]. 64 blocks (one per d)
// x 256 threads; each thread owns 8 k-elements (f2w row = 8 KB / block).
// Deterministic reduction: shfl within wave -> LDS across 4 waves.
// ---------------------------------------------------------------------------
__global__ __launch_bounds__(256) void ffn2_kernel(
    const float* __restrict__ f2w, const float* __restrict__ f2b,
    const float* __restrict__ hbuf, const float* __restrict__ xp,
    float* __restrict__ y_out, int S, int l)
{
    const int tid = threadIdx.x;
    const int d = blockIdx.x;
    const float* wr = f2w + (size_t)(l * 64 + d) * 2048 + tid * 8;
    float4 w0 = ((const float4*)wr)[0];
    float4 w1 = ((const float4*)wr)[1];

    __shared__ float sw[4][10];
    for (int s = 0; s < S; s++) {
        const float* hr = hbuf + s * 2048 + tid * 8;
        float4 h0 = ((const float4*)hr)[0];
        float4 h1 = ((const float4*)hr)[1];
        float p = w0.x * h0.x + w0.y * h0.y + w0.z * h0.z + w0.w * h0.w
                + w1.x * h1.x + w1.y * h1.y + w1.z * h1.z + w1.w * h1.w;
        #pragma unroll
        for (int off = 1; off < 64; off <<= 1) p += __shfl_xor(p, off);
        if ((tid & 63) == 0) sw[tid >> 6][s] = p;
    }
    __syncthreads();
    if (tid < S) {
        float v = sw[0][tid] + sw[1][tid] + sw[2][tid] + sw[3][tid];
        y_out[tid * 64 + d] = v + f2b[l * 64 + d] + xp[tid * 64 + d];
    }
}

// ---------------------------------------------------------------------------
// Logits: fuses the final LN2 (layer-1 params) of y's last row, then
// logits[row] = xl . item_emb[row]. 16 lanes/row, float4 loads, one
// atomicMax per block on the packed (value, ~idx) u64.
// ---------------------------------------------------------------------------
__global__ __launch_bounds__(256) void logits_kernel(
    const float* __restrict__ item_emb, const float* __restrict__ y_in,
    const float* __restrict__ l2w1, const float* __restrict__ l2b1,
    float* __restrict__ out, unsigned long long* __restrict__ best, int S)
{
    const int tid = threadIdx.x;
    __shared__ float xl[64];
    if (tid < 64) {
        float v = y_in[(S - 1) * 64 + tid];
        float m = v;
        #pragma unroll
        for (int off = 1; off < 64; off <<= 1) m += __shfl_xor(m, off);
        m *= (1.0f / 64.0f);
        float df = v - m;
        float var = df * df;
        #pragma unroll
        for (int off = 1; off < 64; off <<= 1) var += __shfl_xor(var, off);
        var *= (1.0f / 64.0f);
        float r = 1.0f / sqrtf(var + EPS_);
        xl[tid] = df * r * l2w1[tid] + l2b1[tid];
    }
    __syncthreads();

    const int l16 = tid & 15;
    float4 q = ((const float4*)xl)[l16];
    const int group0 = (blockIdx.x * 256 + tid) >> 4;
    const int ngroups = (gridDim.x * 256) >> 4;
    unsigned long long lb = 0ull;

    for (int row = group0; row < V_; row += ngroups) {
        float4 e = ((const float4*)(item_emb + (size_t)row * 64))[l16];
        float p = q.x * e.x + q.y * e.y + q.z * e.z + q.w * e.w;
        p += __shfl_xor(p, 1);
        p += __shfl_xor(p, 2);
        p += __shfl_xor(p, 4);
        p += __shfl_xor(p, 8);
        if (l16 == 0) {
            out[row] = p;
            unsigned long long pk = pack_best(p, row);
            if (pk > lb) lb = pk;
        }
    }

    __shared__ unsigned long long sb[16];
    if (l16 == 0) sb[tid >> 4] = lb;
    __syncthreads();
    if (tid == 0) {
        unsigned long long b = sb[0];
        #pragma unroll
        for (int i = 1; i < 16; i++) b = (sb[i] > b) ? sb[i] : b;
        atomicMax(best, b);
    }
}

__global__ void finalize_kernel(const unsigned long long* __restrict__ bp,
                                float* __restrict__ gen_out) {
    if (threadIdx.x == 0) {
        gen_out[STEPS_ - 1] = (float)unpack_idx(bp[STEPS_ - 1]);
    }
}

extern "C" void kernel_launch(void* const* d_in, const int* in_sizes, int n_in,
                              void* d_out, int out_size, void* d_ws, size_t ws_size,
                              hipStream_t stream) {
    const float* ht       = (const float*)d_in[0];
    const float* item_emb = (const float*)d_in[1];
    const float* pos_emb  = (const float*)d_in[2];
    const float* ipw      = (const float*)d_in[3];
    const float* ipb      = (const float*)d_in[4];
    const float* ow       = (const float*)d_in[5];
    const float* ob       = (const float*)d_in[6];
    const float* l1w      = (const float*)d_in[7];
    const float* l1b      = (const float*)d_in[8];
    const float* l2w      = (const float*)d_in[9];
    const float* l2b      = (const float*)d_in[10];
    const float* f1w      = (const float*)d_in[11];
    const float* f1b      = (const float*)d_in[12];
    const float* f2w      = (const float*)d_in[13];
    const float* f2b      = (const float*)d_in[14];

    float* out = (float*)d_out;
    char* ws = (char*)d_ws;
    unsigned long long* bp = (unsigned long long*)ws;   // [0,128)   16 x u64
    int* gen_idx  = (int*)(ws + 128);                   // [128,192) 16 x i32
    float* xp     = (float*)(ws + 256);                 // [256,2816)  10x64
    float* ybuf   = (float*)(ws + 2816);                // [2816,5376) 10x64
    float* hbuf   = (float*)(ws + 5632);                // [5632,+80KB) 10x2048
    float* gen_out = out + (size_t)STEPS_ * V_;

    init_kernel<<<1, 64, 0, stream>>>(bp);
    for (int t = 0; t < STEPS_; t++) {
        const int S = t + 1;
        for (int l = 0; l < 2; l++) {
            attn_kernel<<<1, 1024, 0, stream>>>(
                ht, item_emb, pos_emb, ipw, ipb, ow, ob, l1w, l1b,
                l2w /*layer0 LN2*/, l2b, bp, gen_idx, ybuf, xp, gen_out, t, l);
            ffn1_kernel<<<128, 256, 0, stream>>>(f1w, f1b, xp, hbuf, S, l);
            ffn2_kernel<<<64, 256, 0, stream>>>(f2w, f2b, hbuf, xp, ybuf, S, l);
        }
        logits_kernel<<<2048, 256, 0, stream>>>(
            item_emb, ybuf, l2w + 64, l2b + 64, out + (size_t)t * V_, bp + t, S);
    }
    finalize_kernel<<<1, 64, 0, stream>>>(bp, gen_out);
}

// Round 3
// 1028.750 us; speedup vs baseline: 4.6925x; 1.3589x over previous
//
#include <hip/hip_runtime.h>

typedef unsigned long long u64;
typedef unsigned int u32;
typedef unsigned short u16;

#define V_ 1000000
#define STEPS_ 10
#define EPS_ 1e-5f
#define MARGIN_ 0.02f

// ---------------------------------------------------------------------------
// Packed (value, ~idx) so u64 max == argmax with lowest-index tie-break.
// ---------------------------------------------------------------------------
__device__ __forceinline__ u64 pack_best(float v, int idx) {
    u32 u = __float_as_uint(v);
    u = (u & 0x80000000u) ? ~u : (u | 0x80000000u);
    return ((u64)u << 32) | (u64)(~(u32)idx);
}
__device__ __forceinline__ int unpack_idx(u64 p) { return (int)(~(u32)p); }
__device__ __forceinline__ float unpack_val(u64 p) {
    u32 hi = (u32)(p >> 32);
    return __uint_as_float((hi & 0x80000000u) ? (hi ^ 0x80000000u) : ~hi);
}
__device__ __forceinline__ u64 shfl_xor_u64(u64 v, int m) {
    u32 lo = (u32)v, hi = (u32)(v >> 32);
    lo = (u32)__shfl_xor((int)lo, m);
    hi = (u32)__shfl_xor((int)hi, m);
    return ((u64)hi << 32) | lo;
}
__device__ __forceinline__ u16 f2bf(float f) {  // RNE fp32 -> bf16
    u32 u = __float_as_uint(f);
    u += 0x7fffu + ((u >> 16) & 1u);
    return (u16)(u >> 16);
}
__device__ __forceinline__ float bf_lo(u32 u) { return __uint_as_float(u << 16); }
__device__ __forceinline__ float bf_hi(u32 u) { return __uint_as_float(u & 0xffff0000u); }

// ---------------------------------------------------------------------------
// Exact argmax resolve (blockDim=256): approx block-bests in cand[2048] came
// from bf16 logits; rescore every candidate within MARGIN of the approx max
// using fp32 item_emb. xl = LN2(y_last) with layer-1 params.
// ---------------------------------------------------------------------------
__device__ int resolve_argmax(const u64* __restrict__ cand,
                              const float* __restrict__ item_emb,
                              const float* __restrict__ y_last,
                              const float* __restrict__ lnw,
                              const float* __restrict__ lnb,
                              float* s_xl, int* s_list, u64* s_wm,
                              int* s_cnt, u64* s_best)
{
    const int tid = threadIdx.x;
    if (tid < 64) {
        float v = y_last[tid];
        float m = v;
        #pragma unroll
        for (int o = 1; o < 64; o <<= 1) m += __shfl_xor(m, o);
        m *= (1.f / 64.f);
        float df = v - m;
        float var = df * df;
        #pragma unroll
        for (int o = 1; o < 64; o <<= 1) var += __shfl_xor(var, o);
        var *= (1.f / 64.f);
        s_xl[tid] = df * (1.f / sqrtf(var + EPS_)) * lnw[tid] + lnb[tid];
    }
    if (tid == 0) { *s_cnt = 0; *s_best = 0ull; }
    __syncthreads();

    u64 m = 0ull;
    for (int i = tid; i < 2048; i += 256) { u64 c = cand[i]; if (c > m) m = c; }
    #pragma unroll
    for (int o = 1; o < 64; o <<= 1) { u64 x = shfl_xor_u64(m, o); if (x > m) m = x; }
    if ((tid & 63) == 0) s_wm[tid >> 6] = m;
    __syncthreads();
    if (tid == 0) {
        u64 b = s_wm[0];
        for (int i = 1; i < 4; i++) if (s_wm[i] > b) b = s_wm[i];
        s_wm[0] = b;
    }
    __syncthreads();

    float thr = unpack_val(s_wm[0]) - MARGIN_;
    for (int i = tid; i < 2048; i += 256) {
        if (unpack_val(cand[i]) >= thr) {
            int p = atomicAdd(s_cnt, 1);
            if (p < 64) s_list[p] = unpack_idx(cand[i]);
        }
    }
    __syncthreads();
    int n = *s_cnt; if (n > 64) n = 64;
    const int wid = tid >> 6, lane = tid & 63;
    for (int c = wid; c < n; c += 4) {
        int row = s_list[c];
        float p = s_xl[lane] * item_emb[(size_t)row * 64 + lane];
        #pragma unroll
        for (int o = 1; o < 64; o <<= 1) p += __shfl_xor(p, o);
        if (lane == 0) atomicMax(s_best, pack_best(p, row));
    }
    __syncthreads();
    return unpack_idx(*s_best);
}

// ---------------------------------------------------------------------------
// Layer-0 kernel, 128 blocks x 256. Every block redundantly: resolves the
// previous step's argmax, builds x, runs attention + LN1 (tiny), then
// computes its own 16 FFN1 hidden units for all S rows -> hbuf.
// ---------------------------------------------------------------------------
__global__ __launch_bounds__(256) void attn0_kernel(
    const float* __restrict__ ht, const float* __restrict__ item_emb,
    const float* __restrict__ pos_emb,
    const float* __restrict__ ipw, const float* __restrict__ ipb,
    const float* __restrict__ ow,  const float* __restrict__ ob,
    const float* __restrict__ l1w, const float* __restrict__ l1b,
    const float* __restrict__ l2w1, const float* __restrict__ l2b1,
    const u64* __restrict__ cand, const float* __restrict__ y_last,
    int* __restrict__ gen_idx, float* __restrict__ gen_out,
    const float* __restrict__ f1w, const float* __restrict__ f1b,
    float* __restrict__ xp0, float* __restrict__ hbuf, int t)
{
    const int S = t + 1;
    const int tid = threadIdx.x;
    __shared__ float x[640], qkv[1920], att[400], o_[640], y2[640], xps[640];
    __shared__ float rm[10], rr[10], xl[64];
    __shared__ int list[64], cnt;
    __shared__ u64 wm[4], best;

    int newidx = -1;
    if (t > 0) {
        newidx = resolve_argmax(cand, item_emb, y_last, l2w1, l2b1,
                                xl, list, wm, &cnt, &best);
        if (blockIdx.x == 0 && tid == 0) {
            gen_idx[t - 1] = newidx;
            gen_out[t - 1] = (float)newidx;
        }
    }
    __syncthreads();

    for (int i = tid; i < S * 64; i += 256) {
        int s = i >> 6, d = i & 63;
        float base;
        if (s == 0) base = ht[d];
        else {
            int gi = (s == t) ? newidx : gen_idx[s - 1];
            base = item_emb[(size_t)gi * 64 + d];
        }
        x[i] = base + pos_emb[i];
    }
    __syncthreads();

    // QKV (layer 0)
    for (int i = tid; i < S * 192; i += 256) {
        int s = i / 192, j = i % 192;
        float acc = ipb[j];
        const float4* wr = (const float4*)(ipw + j * 64);
        const float4* xr = (const float4*)(x + s * 64);
        #pragma unroll
        for (int k = 0; k < 16; k++) {
            float4 w4 = wr[k], xv = xr[k];
            acc += w4.x * xv.x + w4.y * xv.y + w4.z * xv.z + w4.w * xv.w;
        }
        qkv[i] = acc;
    }
    __syncthreads();

    for (int i = tid; i < 4 * S * S; i += 256) {
        int h = i / (S * S), r = i % (S * S);
        int si = r / S, ti = r % S;
        const float* qr = qkv + si * 192 + h * 16;
        const float* kr = qkv + ti * 192 + 64 + h * 16;
        float acc = 0.f;
        #pragma unroll
        for (int k = 0; k < 16; k++) acc += qr[k] * kr[k];
        att[(h * S + si) * S + ti] = acc * 0.25f;
    }
    __syncthreads();

    for (int i = tid; i < 4 * S; i += 256) {
        float* row = att + i * S;
        float mx = row[0];
        for (int j = 1; j < S; j++) mx = fmaxf(mx, row[j]);
        float sm = 0.f;
        for (int j = 0; j < S; j++) { float e = expf(row[j] - mx); row[j] = e; sm += e; }
        float inv = 1.f / sm;
        for (int j = 0; j < S; j++) row[j] *= inv;
    }
    __syncthreads();

    for (int i = tid; i < S * 64; i += 256) {
        int si = i >> 6, d = i & 63, h = d >> 4, dh = d & 15;
        const float* ar = att + (h * S + si) * S;
        float acc = 0.f;
        for (int ti = 0; ti < S; ti++) acc += ar[ti] * qkv[ti * 192 + 128 + h * 16 + dh];
        o_[i] = acc;
    }
    __syncthreads();

    for (int i = tid; i < S * 64; i += 256) {
        int s = i >> 6, d = i & 63;
        float acc = ob[d] + x[i];
        const float4* wr = (const float4*)(ow + d * 64);
        const float4* orow = (const float4*)(o_ + s * 64);
        #pragma unroll
        for (int k = 0; k < 16; k++) {
            float4 w4 = wr[k], ov = orow[k];
            acc += w4.x * ov.x + w4.y * ov.y + w4.z * ov.z + w4.w * ov.w;
        }
        y2[i] = acc;
    }
    __syncthreads();

    if (tid < S) {
        const float* yr = y2 + tid * 64;
        float m = 0.f;
        for (int k = 0; k < 64; k++) m += yr[k];
        m *= (1.f / 64.f);
        float v = 0.f;
        for (int k = 0; k < 64; k++) { float df = yr[k] - m; v += df * df; }
        rm[tid] = m;
        rr[tid] = 1.f / sqrtf(v * (1.f / 64.f) + EPS_);
    }
    __syncthreads();
    for (int i = tid; i < S * 64; i += 256) {
        int s = i >> 6, d = i & 63;
        float v = (y2[i] - rm[s]) * rr[s] * l1w[d] + l1b[d];
        xps[i] = v;
        xp0[i] = v;
    }
    __syncthreads();

    // FFN1: this block's 16 hidden units, all S rows
    const int jl = tid >> 4, kp = tid & 15;
    const int j = blockIdx.x * 16 + jl;
    float4 w4 = ((const float4*)(f1w + (size_t)j * 64))[kp];
    float b1 = f1b[j];
    for (int s = 0; s < S; s++) {
        float4 xv = ((const float4*)(xps + s * 64))[kp];
        float p = w4.x * xv.x + w4.y * xv.y + w4.z * xv.z + w4.w * xv.w;
        p += __shfl_xor(p, 1);
        p += __shfl_xor(p, 2);
        p += __shfl_xor(p, 4);
        p += __shfl_xor(p, 8);
        if (kp == 0) hbuf[s * 2048 + j] = fmaxf(p + b1, 0.f);
    }
}

// ---------------------------------------------------------------------------
// Layer-0 FFN2 (all rows): 64 blocks, one output dim each.
// ---------------------------------------------------------------------------
__global__ __launch_bounds__(256) void ffn2_full_kernel(
    const float* __restrict__ f2w0, const float* __restrict__ f2b0,
    const float* __restrict__ hbuf, const float* __restrict__ xp0,
    float* __restrict__ y0, int S)
{
    const int tid = threadIdx.x, d = blockIdx.x;
    const float4* w4 = (const float4*)(f2w0 + (size_t)d * 2048 + tid * 8);
    float4 w0 = w4[0], w1 = w4[1];
    __shared__ float sw[4][10];
    for (int s = 0; s < S; s++) {
        const float4* h4 = (const float4*)(hbuf + s * 2048 + tid * 8);
        float4 h0 = h4[0], h1 = h4[1];
        float p = w0.x * h0.x + w0.y * h0.y + w0.z * h0.z + w0.w * h0.w
                + w1.x * h1.x + w1.y * h1.y + w1.z * h1.z + w1.w * h1.w;
        #pragma unroll
        for (int o = 1; o < 64; o <<= 1) p += __shfl_xor(p, o);
        if ((tid & 63) == 0) sw[tid >> 6][s] = p;
    }
    __syncthreads();
    if (tid < S)
        y0[tid * 64 + d] = sw[0][tid] + sw[1][tid] + sw[2][tid] + sw[3][tid]
                         + f2b0[d] + xp0[tid * 64 + d];
}

// ---------------------------------------------------------------------------
// Layer-1 kernel, 128 blocks x 256: redundant LN2(y0) + attention computing
// ONLY the last row's output (next step never reads other rows), LN1 of the
// last row, then this block's 16 FFN1 hidden units for the last row.
// ---------------------------------------------------------------------------
__global__ __launch_bounds__(256) void attn1_kernel(
    const float* __restrict__ y0,
    const float* __restrict__ l2w0, const float* __restrict__ l2b0,
    const float* __restrict__ ipw1, const float* __restrict__ ipb1,
    const float* __restrict__ ow1,  const float* __restrict__ ob1,
    const float* __restrict__ l1w1, const float* __restrict__ l1b1,
    const float* __restrict__ f1w1, const float* __restrict__ f1b1,
    float* __restrict__ xp1_last, float* __restrict__ hbuf, int S)
{
    const int tid = threadIdx.x;
    __shared__ float y0s[640], x1[640], qkv[1920], att[40], ol[64], y2l[64], xpl[64];
    __shared__ float rm[10], rr[10];

    for (int i = tid; i < S * 64; i += 256) y0s[i] = y0[i];
    __syncthreads();
    if (tid < S) {
        const float* yr = y0s + tid * 64;
        float m = 0.f;
        for (int k = 0; k < 64; k++) m += yr[k];
        m *= (1.f / 64.f);
        float v = 0.f;
        for (int k = 0; k < 64; k++) { float df = yr[k] - m; v += df * df; }
        rm[tid] = m;
        rr[tid] = 1.f / sqrtf(v * (1.f / 64.f) + EPS_);
    }
    __syncthreads();
    for (int i = tid; i < S * 64; i += 256) {
        int s = i >> 6, d = i & 63;
        x1[i] = (y0s[i] - rm[s]) * rr[s] * l2w0[d] + l2b0[d];
    }
    __syncthreads();

    for (int i = tid; i < S * 192; i += 256) {
        int s = i / 192, j = i % 192;
        float acc = ipb1[j];
        const float4* wr = (const float4*)(ipw1 + j * 64);
        const float4* xr = (const float4*)(x1 + s * 64);
        #pragma unroll
        for (int k = 0; k < 16; k++) {
            float4 w4 = wr[k], xv = xr[k];
            acc += w4.x * xv.x + w4.y * xv.y + w4.z * xv.z + w4.w * xv.w;
        }
        qkv[i] = acc;
    }
    __syncthreads();

    // scores: last query row only
    for (int i = tid; i < 4 * S; i += 256) {
        int h = i / S, ti = i % S;
        const float* qr = qkv + (S - 1) * 192 + h * 16;
        const float* kr = qkv + ti * 192 + 64 + h * 16;
        float acc = 0.f;
        #pragma unroll
        for (int k = 0; k < 16; k++) acc += qr[k] * kr[k];
        att[h * S + ti] = acc * 0.25f;
    }
    __syncthreads();
    if (tid < 4) {
        float* row = att + tid * S;
        float mx = row[0];
        for (int j = 1; j < S; j++) mx = fmaxf(mx, row[j]);
        float sm = 0.f;
        for (int j = 0; j < S; j++) { float e = expf(row[j] - mx); row[j] = e; sm += e; }
        float inv = 1.f / sm;
        for (int j = 0; j < S; j++) row[j] *= inv;
    }
    __syncthreads();
    if (tid < 64) {
        int h = tid >> 4, dh = tid & 15;
        const float* ar = att + h * S;
        float acc = 0.f;
        for (int ti = 0; ti < S; ti++) acc += ar[ti] * qkv[ti * 192 + 128 + h * 16 + dh];
        ol[tid] = acc;
    }
    __syncthreads();
    if (tid < 64) {
        float acc = ob1[tid] + x1[(S - 1) * 64 + tid];
        const float* wr = ow1 + tid * 64;
        for (int k = 0; k < 64; k++) acc += ol[k] * wr[k];
        y2l[tid] = acc;
    }
    __syncthreads();
    if (tid < 64) {
        float v = y2l[tid];
        float m = v;
        #pragma unroll
        for (int o = 1; o < 64; o <<= 1) m += __shfl_xor(m, o);
        m *= (1.f / 64.f);
        float df = v - m;
        float var = df * df;
        #pragma unroll
        for (int o = 1; o < 64; o <<= 1) var += __shfl_xor(var, o);
        float r = 1.f / sqrtf(var * (1.f / 64.f) + EPS_);
        float xv = df * r * l1w1[tid] + l1b1[tid];
        xpl[tid] = xv;
        xp1_last[tid] = xv;
    }
    __syncthreads();

    const int jl = tid >> 4, kp = tid & 15;
    const int j = blockIdx.x * 16 + jl;
    float4 w4 = ((const float4*)(f1w1 + (size_t)j * 64))[kp];
    float4 xv = ((const float4*)xpl)[kp];
    float p = w4.x * xv.x + w4.y * xv.y + w4.z * xv.z + w4.w * xv.w;
    p += __shfl_xor(p, 1);
    p += __shfl_xor(p, 2);
    p += __shfl_xor(p, 4);
    p += __shfl_xor(p, 8);
    if (kp == 0) hbuf[j] = fmaxf(p + f1b1[j], 0.f);
}

// ---------------------------------------------------------------------------
// Layer-1 FFN2, last row only: 64 blocks, one output dim each -> y_last[64].
// ---------------------------------------------------------------------------
__global__ __launch_bounds__(256) void ffn2_last_kernel(
    const float* __restrict__ f2w1, const float* __restrict__ f2b1,
    const float* __restrict__ hbuf, const float* __restrict__ xp1_last,
    float* __restrict__ y_last)
{
    const int tid = threadIdx.x, d = blockIdx.x;
    const float4* w4 = (const float4*)(f2w1 + (size_t)d * 2048 + tid * 8);
    const float4* h4 = (const float4*)(hbuf + tid * 8);
    float4 w0 = w4[0], w1 = w4[1], h0 = h4[0], h1 = h4[1];
    float p = w0.x * h0.x + w0.y * h0.y + w0.z * h0.z + w0.w * h0.w
            + w1.x * h1.x + w1.y * h1.y + w1.z * h1.z + w1.w * h1.w;
    #pragma unroll
    for (int o = 1; o < 64; o <<= 1) p += __shfl_xor(p, o);
    __shared__ float sw[4];
    if ((tid & 63) == 0) sw[tid >> 6] = p;
    __syncthreads();
    if (tid == 0) y_last[d] = sw[0] + sw[1] + sw[2] + sw[3] + f2b1[d] + xp1_last[d];
}

// ---------------------------------------------------------------------------
// Step-0 logits: fp32 read (exact) + fused bf16 conversion of item_emb.
// 16 lanes/row, float4. Per-block best -> cand[blockIdx].
// ---------------------------------------------------------------------------
__global__ __launch_bounds__(256) void logits_f32_kernel(
    const float* __restrict__ item_emb, const float* __restrict__ y_last,
    const float* __restrict__ lnw, const float* __restrict__ lnb,
    float* __restrict__ out, u64* __restrict__ cand, u16* __restrict__ emb16)
{
    const int tid = threadIdx.x;
    __shared__ float xl[64];
    if (tid < 64) {
        float v = y_last[tid];
        float m = v;
        #pragma unroll
        for (int o = 1; o < 64; o <<= 1) m += __shfl_xor(m, o);
        m *= (1.f / 64.f);
        float df = v - m;
        float var = df * df;
        #pragma unroll
        for (int o = 1; o < 64; o <<= 1) var += __shfl_xor(var, o);
        float r = 1.f / sqrtf(var * (1.f / 64.f) + EPS_);
        xl[tid] = df * r * lnw[tid] + lnb[tid];
    }
    __syncthreads();

    const int l16 = tid & 15;
    float4 q = ((const float4*)xl)[l16];
    const int group0 = (blockIdx.x * 256 + tid) >> 4;
    const int ngroups = (gridDim.x * 256) >> 4;
    u64 lb = 0ull;

    for (int row = group0; row < V_; row += ngroups) {
        float4 e = ((const float4*)(item_emb + (size_t)row * 64))[l16];
        ushort4 us;
        us.x = f2bf(e.x); us.y = f2bf(e.y); us.z = f2bf(e.z); us.w = f2bf(e.w);
        *(ushort4*)(emb16 + (size_t)row * 64 + l16 * 4) = us;
        float p = q.x * e.x + q.y * e.y + q.z * e.z + q.w * e.w;
        p += __shfl_xor(p, 1);
        p += __shfl_xor(p, 2);
        p += __shfl_xor(p, 4);
        p += __shfl_xor(p, 8);
        if (l16 == 0) {
            out[row] = p;
            u64 pk = pack_best(p, row);
            if (pk > lb) lb = pk;
        }
    }
    #pragma unroll
    for (int o = 1; o < 64; o <<= 1) { u64 x = shfl_xor_u64(lb, o); if (x > lb) lb = x; }
    __shared__ u64 sb[4];
    if ((tid & 63) == 0) sb[tid >> 6] = lb;
    __syncthreads();
    if (tid == 0) {
        u64 b = sb[0];
        for (int i = 1; i < 4; i++) if (sb[i] > b) b = sb[i];
        cand[blockIdx.x] = b;
    }
}

// ---------------------------------------------------------------------------
// Steps 1..9 logits from bf16 copy: 8 lanes/row, uint4 (16B) loads.
// ---------------------------------------------------------------------------
__global__ __launch_bounds__(256) void logits_bf16_kernel(
    const u16* __restrict__ emb16, const float* __restrict__ y_last,
    const float* __restrict__ lnw, const float* __restrict__ lnb,
    float* __restrict__ out, u64* __restrict__ cand)
{
    const int tid = threadIdx.x;
    __shared__ float xl[64];
    if (tid < 64) {
        float v = y_last[tid];
        float m = v;
        #pragma unroll
        for (int o = 1; o < 64; o <<= 1) m += __shfl_xor(m, o);
        m *= (1.f / 64.f);
        float df = v - m;
        float var = df * df;
        #pragma unroll
        for (int o = 1; o < 64; o <<= 1) var += __shfl_xor(var, o);
        float r = 1.f / sqrtf(var * (1.f / 64.f) + EPS_);
        xl[tid] = df * r * lnw[tid] + lnb[tid];
    }
    __syncthreads();

    const int j8 = tid & 7;
    float q[8];
    #pragma unroll
    for (int i = 0; i < 8; i++) q[i] = xl[j8 * 8 + i];
    const int group0 = (blockIdx.x * 256 + tid) >> 3;
    const int ngroups = (gridDim.x * 256) >> 3;
    const uint4* base = (const uint4*)emb16;
    u64 lb = 0ull;

    for (int row = group0; row < V_; row += ngroups) {
        uint4 u = base[(size_t)row * 8 + j8];
        float p = q[0] * bf_lo(u.x) + q[1] * bf_hi(u.x)
                + q[2] * bf_lo(u.y) + q[3] * bf_hi(u.y)
                + q[4] * bf_lo(u.z) + q[5] * bf_hi(u.z)
                + q[6] * bf_lo(u.w) + q[7] * bf_hi(u.w);
        p += __shfl_xor(p, 1);
        p += __shfl_xor(p, 2);
        p += __shfl_xor(p, 4);
        if (j8 == 0) {
            out[row] = p;
            u64 pk = pack_best(p, row);
            if (pk > lb) lb = pk;
        }
    }
    #pragma unroll
    for (int o = 1; o < 64; o <<= 1) { u64 x = shfl_xor_u64(lb, o); if (x > lb) lb = x; }
    __shared__ u64 sb[4];
    if ((tid & 63) == 0) sb[tid >> 6] = lb;
    __syncthreads();
    if (tid == 0) {
        u64 b = sb[0];
        for (int i = 1; i < 4; i++) if (sb[i] > b) b = sb[i];
        cand[blockIdx.x] = b;
    }
}

__global__ __launch_bounds__(256) void finalize_kernel(
    const u64* __restrict__ cand, const float* __restrict__ item_emb,
    const float* __restrict__ y_last,
    const float* __restrict__ lnw, const float* __restrict__ lnb,
    float* __restrict__ gen_out)
{
    __shared__ float xl[64];
    __shared__ int list[64], cnt;
    __shared__ u64 wm[4], best;
    int r = resolve_argmax(cand, item_emb, y_last, lnw, lnb, xl, list, wm, &cnt, &best);
    if (threadIdx.x == 0) gen_out[STEPS_ - 1] = (float)r;
}

extern "C" void kernel_launch(void* const* d_in, const int* in_sizes, int n_in,
                              void* d_out, int out_size, void* d_ws, size_t ws_size,
                              hipStream_t stream) {
    const float* ht       = (const float*)d_in[0];
    const float* item_emb = (const float*)d_in[1];
    const float* pos_emb  = (const float*)d_in[2];
    const float* ipw      = (const float*)d_in[3];
    const float* ipb      = (const float*)d_in[4];
    const float* ow       = (const float*)d_in[5];
    const float* ob       = (const float*)d_in[6];
    const float* l1w      = (const float*)d_in[7];
    const float* l1b      = (const float*)d_in[8];
    const float* l2w      = (const float*)d_in[9];
    const float* l2b      = (const float*)d_in[10];
    const float* f1w      = (const float*)d_in[11];
    const float* f1b      = (const float*)d_in[12];
    const float* f2w      = (const float*)d_in[13];
    const float* f2b      = (const float*)d_in[14];

    float* out = (float*)d_out;
    char* ws = (char*)d_ws;
    int*   gen_idx = (int*)ws;                 // [0,64)
    float* xp0     = (float*)(ws + 64);        // [64,2624)    10x64
    float* xp1l    = (float*)(ws + 2624);      // [2624,2880)  64
    float* y_last  = (float*)(ws + 2880);      // [2880,3136)  64
    float* y0      = (float*)(ws + 3136);      // [3136,5696)  10x64
    float* hbuf    = (float*)(ws + 8192);      // [8192,90112) 10x2048
    u64*   cand    = (u64*)(ws + 90112);       // [90112,106496) 2048 x u64
    u16*   emb16   = (u16*)(ws + 131072);      // 128 MB bf16 copy of item_emb
    float* gen_out = out + (size_t)STEPS_ * V_;

    for (int t = 0; t < STEPS_; t++) {
        const int S = t + 1;
        attn0_kernel<<<128, 256, 0, stream>>>(
            ht, item_emb, pos_emb, ipw, ipb, ow, ob, l1w, l1b,
            l2w + 64, l2b + 64, cand, y_last, gen_idx, gen_out,
            f1w, f1b, xp0, hbuf, t);
        ffn2_full_kernel<<<64, 256, 0, stream>>>(f2w, f2b, hbuf, xp0, y0, S);
        attn1_kernel<<<128, 256, 0, stream>>>(
            y0, l2w, l2b, ipw + 192 * 64, ipb + 192, ow + 64 * 64, ob + 64,
            l1w + 64, l1b + 64, f1w + 2048 * 64, f1b + 2048, xp1l, hbuf, S);
        ffn2_last_kernel<<<64, 256, 0, stream>>>(
            f2w + (size_t)64 * 2048, f2b + 64, hbuf, xp1l, y_last);
        if (t == 0)
            logits_f32_kernel<<<2048, 256, 0, stream>>>(
                item_emb, y_last, l2w + 64, l2b + 64, out, cand, emb16);
        else
            logits_bf16_kernel<<<2048, 256, 0, stream>>>(
                emb16, y_last, l2w + 64, l2b + 64, out + (size_t)t * V_, cand);
    }
    finalize_kernel<<<1, 256, 0, stream>>>(
        cand, item_emb, y_last, l2w + 64, l2b + 64, gen_out);
}